// Round 9
// baseline (2076.110 us; speedup 1.0000x reference)
//
#include <hip/hip_runtime.h>
#include <math.h>

#define NN    2048      // nodes == hidden
#define TT    64        // horizon
#define KIN   32768     // N_IN * N_NODES
#define KSTAT 30720     // static (non-recurrent) part of W_in columns
#define KPART 8         // K-split for k_pre
#define KC    (KSTAT / KPART)   // 3840
#define RWORDS 640      // dwords per packed int10 row (64 lanes * 10)

typedef unsigned int uint32;

__device__ __forceinline__ float wred(float v){
  #pragma unroll
  for (int m = 32; m > 0; m >>= 1) v += __shfl_xor(v, m, 64);
  return v;
}
__device__ __forceinline__ float wredmax(float v){
  #pragma unroll
  for (int m = 32; m > 0; m >>= 1) v = fmaxf(v, __shfl_xor(v, m, 64));
  return v;
}
__device__ __forceinline__ float sigm(float x){ return 1.0f / (1.0f + expf(-x)); }

__device__ __forceinline__ void load8f(const float* __restrict__ p, float* o){
  float4 a = *(const float4*)p, b = *(const float4*)(p + 4);
  o[0]=a.x; o[1]=a.y; o[2]=a.z; o[3]=a.w; o[4]=b.x; o[5]=b.y; o[6]=b.z; o[7]=b.w;
}

// ---------- single pack kernel for all 4 matrices (int10, per-row scale) ----------
// Lane owns weights {4*(lane+64c)+q : c=0..7,q=0..3}; field order k=4c+q.
// Row storage: plane0 uint4, plane1 uint4, plane2 uint2 (all lane-coalesced).
__global__ void k_pack_all(const float* __restrict__ Wih, const float* __restrict__ Whh,
                           const float* __restrict__ Win, const float* __restrict__ Wout,
                           uint32* __restrict__ PIH, uint32* __restrict__ PHH,
                           uint32* __restrict__ PT,  uint32* __restrict__ PO,
                           float* __restrict__ sc_ih, float* __restrict__ sc_hh,
                           float* __restrict__ sc_t,  float* __restrict__ sc_o)
{
  const int gr   = blockIdx.x * 4 + (threadIdx.x >> 6);   // 0..36863
  const int lane = threadIdx.x & 63;
  const float* src; uint32* dst; float* sc;
  if (gr < 16384){        int r = gr;         src = Wih  + (size_t)r * NN;          dst = PIH + (size_t)r * RWORDS; sc = sc_ih + r; }
  else if (gr < 32768){   int r = gr - 16384; src = Whh  + (size_t)r * NN;          dst = PHH + (size_t)r * RWORDS; sc = sc_hh + r; }
  else if (gr < 34816){   int r = gr - 32768; src = Win  + (size_t)r * KIN + KSTAT; dst = PT  + (size_t)r * RWORDS; sc = sc_t  + r; }
  else {                  int r = gr - 34816; src = Wout + (size_t)r * NN;          dst = PO  + (size_t)r * RWORDS; sc = sc_o  + r; }

  float w[32];
  float m = 0.f;
  #pragma unroll
  for (int c = 0; c < 8; ++c){
    float4 v = *(const float4*)(src + 4 * (lane + (c << 6)));
    w[4*c+0] = v.x; w[4*c+1] = v.y; w[4*c+2] = v.z; w[4*c+3] = v.w;
    m = fmaxf(m, fmaxf(fmaxf(fabsf(v.x), fabsf(v.y)), fmaxf(fabsf(v.z), fabsf(v.w))));
  }
  m = wredmax(m);
  const float inv = (m > 0.f) ? 511.f / m : 0.f;
  if (lane == 0) *sc = (m > 0.f) ? m / 511.f : 0.f;

  uint32 u[10] = {0,0,0,0,0,0,0,0,0,0};
  #pragma unroll
  for (int k = 0; k < 32; ++k){
    int q = (int)rintf(w[k] * inv) + 512;
    q = (q < 0) ? 0 : ((q > 1023) ? 1023 : q);
    uint32 f = (uint32)q;
    int bp = 10 * k, wd = bp >> 5, off = bp & 31;
    u[wd] |= f << off;
    if (off > 22) u[wd + 1] |= f >> (32 - off);
  }
  *(uint4*)(dst + lane * 4)        = make_uint4(u[0], u[1], u[2], u[3]);
  *(uint4*)(dst + 256 + lane * 4)  = make_uint4(u[4], u[5], u[6], u[7]);
  *(uint2*)(dst + 512 + lane * 2)  = make_uint2(u[8], u[9]);
}

// ---------- packed int10 dot: one wave, one row of 2048; returns UNSCALED sum ----------
__device__ __forceinline__ float dot10(const uint32* __restrict__ base, int row,
                                       const float4* __restrict__ v4, int lane){
  const uint32* p = base + (size_t)row * RWORDS;
  uint4 A = *(const uint4*)(p + lane * 4);
  uint4 B = *(const uint4*)(p + 256 + lane * 4);
  uint2 C = *(const uint2*)(p + 512 + lane * 2);
  uint32 u[10] = {A.x,A.y,A.z,A.w, B.x,B.y,B.z,B.w, C.x,C.y};
  float acc = 0.f;
  #pragma unroll
  for (int c = 0; c < 8; ++c){
    float4 v = v4[lane + (c << 6)];
    float vv[4] = {v.x, v.y, v.z, v.w};
    #pragma unroll
    for (int q = 0; q < 4; ++q){
      int k = 4 * c + q, bp = 10 * k, wd = bp >> 5, off = bp & 31;
      uint32 f = u[wd] >> off;
      if (off > 22) f |= u[wd + 1] << (32 - off);   // folds at compile time
      f &= 1023u;
      acc = fmaf((float)((int)f - 512), vv[q], acc);
    }
  }
  return acc;
}

// ---------- gather static input matrix S[k][t] ----------
__global__ void k_gather(const float* __restrict__ coords, const float* __restrict__ env,
                         const float* __restrict__ dusk, const float* __restrict__ dawn,
                         float* __restrict__ S)
{
  int idx = blockIdx.x * 256 + threadIdx.x;
  int k = idx >> 6, t = idx & 63;
  float v;
  if (k < 4096)        v = coords[k];
  else if (k < 26624)  v = env[(size_t)(k - 4096) * 65 + t + 1];
  else if (k < 28672)  v = dusk[(size_t)(k - 26624) * 64 + t];
  else                 v = dawn[(size_t)(k - 28672) * 65 + t + 1];
  S[idx] = v;
}

// ---------- tiled GEMM: P[part][r][t] = sum_{k in part} W_in[r][k] * S[k][t] ----------
__global__ void k_pre(const float* __restrict__ Win, const float* __restrict__ S,
                      float* __restrict__ P)
{
  __shared__ float Wt[16 * 68];
  __shared__ float St[64 * 68];
  const int tid = threadIdx.x;
  const int rb  = blockIdx.x * 16;
  const int kp  = blockIdx.y;
  const int rc  = tid >> 4;
  const int t4  = (tid & 15) * 4;
  float4 acc = make_float4(0.f, 0.f, 0.f, 0.f);

  for (int kt = 0; kt < KC; kt += 64){
    const int kb = kp * KC + kt;
    __syncthreads();
    *(float4*)(Wt + rc * 68 + t4) =
        *(const float4*)(Win + (size_t)(rb + rc) * KIN + kb + t4);
    #pragma unroll
    for (int jj = 0; jj < 4; ++jj){
      int li = jj * 1024 + tid * 4;
      int kr = li >> 6, tc = li & 63;
      *(float4*)(St + kr * 68 + tc) =
          *(const float4*)(S + (size_t)(kb + kr) * 64 + tc);
    }
    __syncthreads();
    #pragma unroll
    for (int k = 0; k < 64; ++k){
      float w = Wt[rc * 68 + k];
      float4 s = *(const float4*)(St + k * 68 + t4);
      acc.x = fmaf(w, s.x, acc.x);
      acc.y = fmaf(w, s.y, acc.y);
      acc.z = fmaf(w, s.z, acc.z);
      acc.w = fmaf(w, s.w, acc.w);
    }
  }
  *(float4*)(P + ((size_t)kp * NN + rb + rc) * TT + t4) = acc;
}

// ---------- U reduce + state/output init (fused) ----------
__global__ void k_reduce_init(const float* __restrict__ P, const float* __restrict__ bin,
                              float* __restrict__ U, const float* __restrict__ x,
                              float* __restrict__ xs, float* __restrict__ h0b,
                              float* __restrict__ h1b, float* __restrict__ c0,
                              float* __restrict__ c1, float* __restrict__ out)
{
  int i = blockIdx.x * 256 + threadIdx.x;            // 131072 total
  float s = bin[i >> 6];
  #pragma unroll
  for (int p = 0; p < KPART; ++p) s += P[(size_t)p * NN * TT + i];
  U[i] = s;
  if (i < NN){
    float x0 = x[(size_t)i * (TT + 1)];
    xs[i] = x0;
    out[(size_t)i * (TT + 1)] = x0;
    h0b[i] = 0.f; h0b[NN + i] = 0.f;
    h1b[i] = 0.f; h1b[NN + i] = 0.f;
    c0[i] = 0.f;  c1[i] = 0.f;
  }
}

// ---------- stage A: lin[j] = U[j][t] + scale_t[j] * (PT[j,:] . xs) ----------
__global__ void k_lin10(const uint32* __restrict__ PT, const float* __restrict__ sc_t,
                        const float* __restrict__ U, const float* __restrict__ xs,
                        float* __restrict__ lin, int t)
{
  __shared__ float4 xv[512];
  const int tid  = threadIdx.x;
  #pragma unroll
  for (int s = 0; s < 2; ++s) xv[tid + s * 256] = ((const float4*)xs)[tid + s * 256];
  __syncthreads();
  const int j    = blockIdx.x * 4 + (tid >> 6);
  const int lane = tid & 63;
  float acc = wred(dot10(PT, j, xv, lane));
  if (lane == 0) lin[j] = U[(size_t)j * TT + t] + sc_t[j] * acc;
}

// ---------- LSTM layer: block per unit j, wave g per gate; inputs staged in LDS ----------
__global__ void k_lstm10(const uint32* __restrict__ Pih, const uint32* __restrict__ Phh,
                         const float* __restrict__ sc_ih, const float* __restrict__ sc_hh,
                         const float* __restrict__ bih_l, const float* __restrict__ bhh_l,
                         const float* __restrict__ vin, const float* __restrict__ hprev,
                         float* __restrict__ c, float* __restrict__ hout)
{
  __shared__ float4 vs[512];
  __shared__ float4 hs[512];
  __shared__ float gsm[4];
  const int tid = threadIdx.x;
  #pragma unroll
  for (int s = 0; s < 2; ++s){
    vs[tid + s * 256] = ((const float4*)vin)[tid + s * 256];
    hs[tid + s * 256] = ((const float4*)hprev)[tid + s * 256];
  }
  __syncthreads();
  const int j    = blockIdx.x;
  const int g    = tid >> 6;
  const int lane = tid & 63;
  const int row  = g * NN + j;
  float a1 = dot10(Pih, row, vs, lane);
  float a2 = dot10(Phh, row, hs, lane);
  float acc = wred(sc_ih[row] * a1 + sc_hh[row] * a2);
  if (lane == 0) gsm[g] = acc + bih_l[g * NN + j] + bhh_l[g * NN + j];
  __syncthreads();
  if (tid == 0){
    float gi = sigm(gsm[0]);
    float gf = sigm(gsm[1]);
    float gg = tanhf(gsm[2]);
    float go = sigm(gsm[3]);
    float cn = fmaf(gf, c[j], gi * gg);
    c[j] = cn;
    hout[j] = go * tanhf(cn);
  }
}

// ---------- stage D: x += tanh(scale_o[j]*(PO[j,:] . h1) + b_out) ----------
__global__ void k_xout10(const uint32* __restrict__ PO, const float* __restrict__ sc_o,
                         const float* __restrict__ bout, const float* __restrict__ h1,
                         float* __restrict__ xs, float* __restrict__ out, int t)
{
  __shared__ float4 hv[512];
  const int tid = threadIdx.x;
  #pragma unroll
  for (int s = 0; s < 2; ++s) hv[tid + s * 256] = ((const float4*)h1)[tid + s * 256];
  __syncthreads();
  const int j    = blockIdx.x * 4 + (tid >> 6);
  const int lane = tid & 63;
  float acc = wred(dot10(PO, j, hv, lane));
  if (lane == 0){
    float xn = xs[j] + tanhf(sc_o[j] * acc + bout[j]);
    xs[j] = xn;
    out[(size_t)j * (TT + 1) + t + 1] = xn;
  }
}

// ---------- f32 fallback kernels (used only if ws too small) ----------
template<typename WT>
__global__ void k_lin_t(const WT* __restrict__ Wtail, size_t wstride,
                        const float* __restrict__ U, const float* __restrict__ xs,
                        float* __restrict__ lin, int t)
{
  const int j    = blockIdx.x * 4 + (threadIdx.x >> 6);
  const int lane = threadIdx.x & 63;
  const WT* w = Wtail + (size_t)j * wstride + lane * 8;
  const float* xv = xs + lane * 8;
  float acc = 0.f;
  #pragma unroll
  for (int ch = 0; ch < 4; ++ch){
    float wf[8], vf[8];
    load8f(w + ch * 512, wf);
    load8f(xv + ch * 512, vf);
    #pragma unroll
    for (int q = 0; q < 8; ++q) acc = fmaf(wf[q], vf[q], acc);
  }
  acc = wred(acc);
  if (lane == 0) lin[j] = U[(size_t)j * TT + t] + acc;
}

template<typename WT>
__global__ void k_lstm_t(const WT* __restrict__ Wih_l, const WT* __restrict__ Whh_l,
                         const float* __restrict__ bih_l, const float* __restrict__ bhh_l,
                         const float* __restrict__ vin, const float* __restrict__ hprev,
                         float* __restrict__ c, float* __restrict__ hout)
{
  __shared__ float gsm[4];
  const int j    = blockIdx.x;
  const int g    = threadIdx.x >> 6;
  const int lane = threadIdx.x & 63;
  const WT* wi = Wih_l + (size_t)(g * NN + j) * NN + lane * 8;
  const WT* wh = Whh_l + (size_t)(g * NN + j) * NN + lane * 8;
  const float* vi = vin + lane * 8;
  const float* hp = hprev + lane * 8;
  float acc = 0.f;
  #pragma unroll
  for (int ch = 0; ch < 4; ++ch){
    float w1[8], w2[8], v1[8], v2[8];
    load8f(wi + ch * 512, w1); load8f(vi + ch * 512, v1);
    load8f(wh + ch * 512, w2); load8f(hp + ch * 512, v2);
    #pragma unroll
    for (int q = 0; q < 8; ++q) acc = fmaf(w1[q], v1[q], fmaf(w2[q], v2[q], acc));
  }
  acc = wred(acc);
  if (lane == 0) gsm[g] = acc + bih_l[g * NN + j] + bhh_l[g * NN + j];
  __syncthreads();
  if (threadIdx.x == 0){
    float gi = sigm(gsm[0]);
    float gf = sigm(gsm[1]);
    float gg = tanhf(gsm[2]);
    float go = sigm(gsm[3]);
    float cn = fmaf(gf, c[j], gi * gg);
    c[j] = cn;
    hout[j] = go * tanhf(cn);
  }
}

template<typename WT>
__global__ void k_xout_t(const WT* __restrict__ Wout, const float* __restrict__ bout,
                         const float* __restrict__ h1, float* __restrict__ xs,
                         float* __restrict__ out, int t)
{
  const int j    = blockIdx.x * 4 + (threadIdx.x >> 6);
  const int lane = threadIdx.x & 63;
  const WT* w = Wout + (size_t)j * NN + lane * 8;
  const float* hv = h1 + lane * 8;
  float acc = 0.f;
  #pragma unroll
  for (int ch = 0; ch < 4; ++ch){
    float wf[8], vf[8];
    load8f(w + ch * 512, wf);
    load8f(hv + ch * 512, vf);
    #pragma unroll
    for (int q = 0; q < 8; ++q) acc = fmaf(wf[q], vf[q], acc);
  }
  acc = wred(acc);
  if (lane == 0){
    float xn = xs[j] + tanhf(acc + bout[j]);
    xs[j] = xn;
    out[(size_t)j * (TT + 1) + t + 1] = xn;
  }
}

extern "C" void kernel_launch(void* const* d_in, const int* in_sizes, int n_in,
                              void* d_out, int out_size, void* d_ws, size_t ws_size,
                              hipStream_t stream)
{
  const float* x      = (const float*)d_in[0];
  const float* coords = (const float*)d_in[1];
  const float* env    = (const float*)d_in[2];
  const float* dusk   = (const float*)d_in[3];
  const float* dawn   = (const float*)d_in[4];
  const float* Win    = (const float*)d_in[5];
  const float* bin    = (const float*)d_in[6];
  const float* Wih    = (const float*)d_in[7];
  const float* Whh    = (const float*)d_in[8];
  const float* bih    = (const float*)d_in[9];
  const float* bhh    = (const float*)d_in[10];
  const float* Wout   = (const float*)d_in[11];
  const float* bout   = (const float*)d_in[12];
  float* out = (float*)d_out;

  // ---- f32 scratch layout
  float* ws  = (float*)d_ws;
  float* S   = ws;                          // 30720*64
  float* P   = S + (size_t)KSTAT * TT;      // 8*2048*64
  float* U   = P + (size_t)KPART * NN * TT; // 131072
  float* lin = U + (size_t)NN * TT;
  float* h0b = lin + NN;
  float* h1b = h0b + 2 * NN;
  float* c0  = h1b + 2 * NN;
  float* c1  = c0 + NN;
  float* xs  = c1 + NN;
  char*  f32_end = (char*)(xs + NN);
  const size_t f32_bytes = (size_t)(f32_end - (char*)d_ws);

  // ---- packed int10 weights + per-row scales
  const size_t rows_ihhh = (size_t)2 * 4 * NN;          // 16384 rows per matrix
  const size_t pw_ihhh   = rows_ihhh * RWORDS * 4;      // 41.9 MB each
  const size_t pw_small  = (size_t)NN * RWORDS * 4;     // 5.24 MB each

  uint32* PIH = (uint32*)((char*)d_ws + f32_bytes);
  uint32* PHH = (uint32*)((char*)PIH + pw_ihhh);
  uint32* PT  = (uint32*)((char*)PHH + pw_ihhh);
  uint32* PO  = (uint32*)((char*)PT + pw_small);
  float*  sc_ih = (float*)((char*)PO + pw_small);       // 16384
  float*  sc_hh = sc_ih + rows_ihhh;                    // 16384
  float*  sc_t  = sc_hh + rows_ihhh;                    // 2048
  float*  sc_o  = sc_t + NN;                            // 2048
  const size_t needed = f32_bytes + 2 * pw_ihhh + 2 * pw_small
                      + (2 * rows_ihhh + 2 * NN) * sizeof(float);
  const bool use_q = (ws_size >= needed);

  if (use_q){
    // 16384 + 16384 + 2048 + 2048 = 36864 rows, 4 rows/block
    k_pack_all<<<dim3(36864 / 4), dim3(256), 0, stream>>>(
        Wih, Whh, Win, Wout, PIH, PHH, PT, PO, sc_ih, sc_hh, sc_t, sc_o);
  }

  k_gather<<<dim3((KSTAT * TT) / 256), dim3(256), 0, stream>>>(coords, env, dusk, dawn, S);
  k_pre<<<dim3(128, KPART), dim3(256), 0, stream>>>(Win, S, P);
  k_reduce_init<<<dim3(NN * TT / 256), dim3(256), 0, stream>>>(P, bin, U, x, xs,
                                                               h0b, h1b, c0, c1, out);

  const size_t LROWS = (size_t)4 * NN;   // row offset for layer 1
  for (int t = 0; t < TT; ++t){
    const int p = t & 1;
    float* h0n = h0b + (1 - p) * NN;
    float* h0p = h0b + p * NN;
    float* h1n = h1b + (1 - p) * NN;
    float* h1p = h1b + p * NN;
    if (use_q){
      k_lin10<<<dim3(NN / 4), dim3(256), 0, stream>>>(PT, sc_t, U, xs, lin, t);
      k_lstm10<<<dim3(NN), dim3(256), 0, stream>>>(PIH, PHH, sc_ih, sc_hh,
                                                   bih, bhh, lin, h0p, c0, h0n);
      k_lstm10<<<dim3(NN), dim3(256), 0, stream>>>(PIH + LROWS * RWORDS, PHH + LROWS * RWORDS,
                                                   sc_ih + LROWS, sc_hh + LROWS,
                                                   bih + 4 * NN, bhh + 4 * NN,
                                                   h0n, h1p, c1, h1n);
      k_xout10<<<dim3(NN / 4), dim3(256), 0, stream>>>(PO, sc_o, bout, h1n, xs, out, t);
    } else {
      const size_t LOFF = (size_t)4 * NN * NN;
      k_lin_t<float><<<dim3(NN / 4), dim3(256), 0, stream>>>(Win + KSTAT, (size_t)KIN, U, xs, lin, t);
      k_lstm_t<float><<<dim3(NN), dim3(256), 0, stream>>>(Wih, Whh, bih, bhh,
                                                          lin, h0p, c0, h0n);
      k_lstm_t<float><<<dim3(NN), dim3(256), 0, stream>>>(Wih + LOFF, Whh + LOFF,
                                                          bih + 4 * NN, bhh + 4 * NN,
                                                          h0n, h1p, c1, h1n);
      k_xout_t<float><<<dim3(NN / 4), dim3(256), 0, stream>>>(Wout, bout, h1n, xs, out, t);
    }
  }
}

// Round 10
// 1910.799 us; speedup vs baseline: 1.0865x; 1.0865x over previous
//
#include <hip/hip_runtime.h>
#include <math.h>

#define NN    2048      // nodes == hidden
#define TT    64        // horizon
#define KIN   32768     // N_IN * N_NODES
#define KSTAT 30720     // static (non-recurrent) part of W_in columns
#define KPART 8         // K-split for k_pre
#define KC    (KSTAT / KPART)   // 3840
#define RWORDS 640      // dwords per packed int10 row (64 lanes * 10)

typedef unsigned int uint32;

__device__ __forceinline__ float wred(float v){
  #pragma unroll
  for (int m = 32; m > 0; m >>= 1) v += __shfl_xor(v, m, 64);
  return v;
}
__device__ __forceinline__ float wredmax(float v){
  #pragma unroll
  for (int m = 32; m > 0; m >>= 1) v = fmaxf(v, __shfl_xor(v, m, 64));
  return v;
}
__device__ __forceinline__ float sigm(float x){ return 1.0f / (1.0f + expf(-x)); }

__device__ __forceinline__ void load8f(const float* __restrict__ p, float* o){
  float4 a = *(const float4*)p, b = *(const float4*)(p + 4);
  o[0]=a.x; o[1]=a.y; o[2]=a.z; o[3]=a.w; o[4]=b.x; o[5]=b.y; o[6]=b.z; o[7]=b.w;
}

// ---------- single pack kernel for all 4 matrices (int10, per-row scale) ----------
// Lane owns weights {4*(lane+64c)+q : c=0..7,q=0..3}; field order k=4c+q.
// Row storage: plane0 uint4, plane1 uint4, plane2 uint2 (all lane-coalesced).
__global__ void k_pack_all(const float* __restrict__ Wih, const float* __restrict__ Whh,
                           const float* __restrict__ Win, const float* __restrict__ Wout,
                           uint32* __restrict__ PIH, uint32* __restrict__ PHH,
                           uint32* __restrict__ PT,  uint32* __restrict__ PO,
                           float* __restrict__ sc_ih, float* __restrict__ sc_hh,
                           float* __restrict__ sc_t,  float* __restrict__ sc_o)
{
  const int gr   = blockIdx.x * 4 + (threadIdx.x >> 6);   // 0..36863
  const int lane = threadIdx.x & 63;
  const float* src; uint32* dst; float* sc;
  if (gr < 16384){        int r = gr;         src = Wih  + (size_t)r * NN;          dst = PIH + (size_t)r * RWORDS; sc = sc_ih + r; }
  else if (gr < 32768){   int r = gr - 16384; src = Whh  + (size_t)r * NN;          dst = PHH + (size_t)r * RWORDS; sc = sc_hh + r; }
  else if (gr < 34816){   int r = gr - 32768; src = Win  + (size_t)r * KIN + KSTAT; dst = PT  + (size_t)r * RWORDS; sc = sc_t  + r; }
  else {                  int r = gr - 34816; src = Wout + (size_t)r * NN;          dst = PO  + (size_t)r * RWORDS; sc = sc_o  + r; }

  float w[32];
  float m = 0.f;
  #pragma unroll
  for (int c = 0; c < 8; ++c){
    float4 v = *(const float4*)(src + 4 * (lane + (c << 6)));
    w[4*c+0] = v.x; w[4*c+1] = v.y; w[4*c+2] = v.z; w[4*c+3] = v.w;
    m = fmaxf(m, fmaxf(fmaxf(fabsf(v.x), fabsf(v.y)), fmaxf(fabsf(v.z), fabsf(v.w))));
  }
  m = wredmax(m);
  const float inv = (m > 0.f) ? 511.f / m : 0.f;
  if (lane == 0) *sc = (m > 0.f) ? m / 511.f : 0.f;

  uint32 u[10] = {0,0,0,0,0,0,0,0,0,0};
  #pragma unroll
  for (int k = 0; k < 32; ++k){
    int q = (int)rintf(w[k] * inv) + 512;
    q = (q < 0) ? 0 : ((q > 1023) ? 1023 : q);
    uint32 f = (uint32)q;
    int bp = 10 * k, wd = bp >> 5, off = bp & 31;
    u[wd] |= f << off;
    if (off > 22) u[wd + 1] |= f >> (32 - off);
  }
  *(uint4*)(dst + lane * 4)        = make_uint4(u[0], u[1], u[2], u[3]);
  *(uint4*)(dst + 256 + lane * 4)  = make_uint4(u[4], u[5], u[6], u[7]);
  *(uint2*)(dst + 512 + lane * 2)  = make_uint2(u[8], u[9]);
}

// ---------- packed int10 dot: one wave, one row of 2048; returns UNSCALED sum ----------
__device__ __forceinline__ float dot10(const uint32* __restrict__ base, int row,
                                       const float4* __restrict__ v4, int lane){
  const uint32* p = base + (size_t)row * RWORDS;
  uint4 A = *(const uint4*)(p + lane * 4);
  uint4 B = *(const uint4*)(p + 256 + lane * 4);
  uint2 C = *(const uint2*)(p + 512 + lane * 2);
  uint32 u[10] = {A.x,A.y,A.z,A.w, B.x,B.y,B.z,B.w, C.x,C.y};
  float acc = 0.f;
  #pragma unroll
  for (int c = 0; c < 8; ++c){
    float4 v = v4[lane + (c << 6)];
    float vv[4] = {v.x, v.y, v.z, v.w};
    #pragma unroll
    for (int q = 0; q < 4; ++q){
      int k = 4 * c + q, bp = 10 * k, wd = bp >> 5, off = bp & 31;
      uint32 f = u[wd] >> off;
      if (off > 22) f |= u[wd + 1] << (32 - off);   // folds at compile time
      f &= 1023u;
      acc = fmaf((float)((int)f - 512), vv[q], acc);
    }
  }
  return acc;
}

// ---------- gather static input matrix S[k][t] ----------
__global__ void k_gather(const float* __restrict__ coords, const float* __restrict__ env,
                         const float* __restrict__ dusk, const float* __restrict__ dawn,
                         float* __restrict__ S)
{
  int idx = blockIdx.x * 256 + threadIdx.x;
  int k = idx >> 6, t = idx & 63;
  float v;
  if (k < 4096)        v = coords[k];
  else if (k < 26624)  v = env[(size_t)(k - 4096) * 65 + t + 1];
  else if (k < 28672)  v = dusk[(size_t)(k - 26624) * 64 + t];
  else                 v = dawn[(size_t)(k - 28672) * 65 + t + 1];
  S[idx] = v;
}

// ---------- tiled GEMM: P[part][r][t] = sum_{k in part} W_in[r][k] * S[k][t] ----------
__global__ void k_pre(const float* __restrict__ Win, const float* __restrict__ S,
                      float* __restrict__ P)
{
  __shared__ float Wt[16 * 68];
  __shared__ float St[64 * 68];
  const int tid = threadIdx.x;
  const int rb  = blockIdx.x * 16;
  const int kp  = blockIdx.y;
  const int rc  = tid >> 4;
  const int t4  = (tid & 15) * 4;
  float4 acc = make_float4(0.f, 0.f, 0.f, 0.f);

  for (int kt = 0; kt < KC; kt += 64){
    const int kb = kp * KC + kt;
    __syncthreads();
    *(float4*)(Wt + rc * 68 + t4) =
        *(const float4*)(Win + (size_t)(rb + rc) * KIN + kb + t4);
    #pragma unroll
    for (int jj = 0; jj < 4; ++jj){
      int li = jj * 1024 + tid * 4;
      int kr = li >> 6, tc = li & 63;
      *(float4*)(St + kr * 68 + tc) =
          *(const float4*)(S + (size_t)(kb + kr) * 64 + tc);
    }
    __syncthreads();
    #pragma unroll
    for (int k = 0; k < 64; ++k){
      float w = Wt[rc * 68 + k];
      float4 s = *(const float4*)(St + k * 68 + t4);
      acc.x = fmaf(w, s.x, acc.x);
      acc.y = fmaf(w, s.y, acc.y);
      acc.z = fmaf(w, s.z, acc.z);
      acc.w = fmaf(w, s.w, acc.w);
    }
  }
  *(float4*)(P + ((size_t)kp * NN + rb + rc) * TT + t4) = acc;
}

// ---------- U reduce + state/output init (fused) ----------
__global__ void k_reduce_init(const float* __restrict__ P, const float* __restrict__ bin,
                              float* __restrict__ U, const float* __restrict__ x,
                              float* __restrict__ xs, float* __restrict__ h0b,
                              float* __restrict__ h1b, float* __restrict__ c0,
                              float* __restrict__ c1, float* __restrict__ out)
{
  int i = blockIdx.x * 256 + threadIdx.x;            // 131072 total
  float s = bin[i >> 6];
  #pragma unroll
  for (int p = 0; p < KPART; ++p) s += P[(size_t)p * NN * TT + i];
  U[i] = s;
  if (i < NN){
    float x0 = x[(size_t)i * (TT + 1)];
    xs[i] = x0;
    out[(size_t)i * (TT + 1)] = x0;
    h0b[i] = 0.f; h0b[NN + i] = 0.f;
    h1b[i] = 0.f; h1b[NN + i] = 0.f;
    c0[i] = 0.f;  c1[i] = 0.f;
  }
}

// ---------- stage A: lin[j] = U[j][t] + scale_t[j] * (PT[j,:] . xs) ----------
__global__ void k_lin10(const uint32* __restrict__ PT, const float* __restrict__ sc_t,
                        const float* __restrict__ U, const float* __restrict__ xs,
                        float* __restrict__ lin, int t)
{
  const int j    = blockIdx.x * 4 + (threadIdx.x >> 6);
  const int lane = threadIdx.x & 63;
  float acc = wred(dot10(PT, j, (const float4*)xs, lane));
  if (lane == 0) lin[j] = U[(size_t)j * TT + t] + sc_t[j] * acc;
}

// ---------- LSTM layer: block per unit j, wave g per gate (direct global reads) ----------
__global__ void k_lstm10(const uint32* __restrict__ Pih, const uint32* __restrict__ Phh,
                         const float* __restrict__ sc_ih, const float* __restrict__ sc_hh,
                         const float* __restrict__ bih_l, const float* __restrict__ bhh_l,
                         const float* __restrict__ vin, const float* __restrict__ hprev,
                         float* __restrict__ c, float* __restrict__ hout)
{
  __shared__ float gsm[4];
  const int j    = blockIdx.x;
  const int g    = threadIdx.x >> 6;
  const int lane = threadIdx.x & 63;
  const int row  = g * NN + j;
  float a1 = dot10(Pih, row, (const float4*)vin,   lane);
  float a2 = dot10(Phh, row, (const float4*)hprev, lane);
  float acc = wred(sc_ih[row] * a1 + sc_hh[row] * a2);
  if (lane == 0) gsm[g] = acc + bih_l[g * NN + j] + bhh_l[g * NN + j];
  __syncthreads();
  if (threadIdx.x == 0){
    float gi = sigm(gsm[0]);
    float gf = sigm(gsm[1]);
    float gg = tanhf(gsm[2]);
    float go = sigm(gsm[3]);
    float cn = fmaf(gf, c[j], gi * gg);
    c[j] = cn;
    hout[j] = go * tanhf(cn);
  }
}

// ---------- stage D: x += tanh(scale_o[j]*(PO[j,:] . h1) + b_out) ----------
__global__ void k_xout10(const uint32* __restrict__ PO, const float* __restrict__ sc_o,
                         const float* __restrict__ bout, const float* __restrict__ h1,
                         float* __restrict__ xs, float* __restrict__ out, int t)
{
  const int j    = blockIdx.x * 4 + (threadIdx.x >> 6);
  const int lane = threadIdx.x & 63;
  float acc = wred(dot10(PO, j, (const float4*)h1, lane));
  if (lane == 0){
    float xn = xs[j] + tanhf(sc_o[j] * acc + bout[j]);
    xs[j] = xn;
    out[(size_t)j * (TT + 1) + t + 1] = xn;
  }
}

// ---------- f32 fallback kernels (used only if ws too small) ----------
template<typename WT>
__global__ void k_lin_t(const WT* __restrict__ Wtail, size_t wstride,
                        const float* __restrict__ U, const float* __restrict__ xs,
                        float* __restrict__ lin, int t)
{
  const int j    = blockIdx.x * 4 + (threadIdx.x >> 6);
  const int lane = threadIdx.x & 63;
  const WT* w = Wtail + (size_t)j * wstride + lane * 8;
  const float* xv = xs + lane * 8;
  float acc = 0.f;
  #pragma unroll
  for (int ch = 0; ch < 4; ++ch){
    float wf[8], vf[8];
    load8f(w + ch * 512, wf);
    load8f(xv + ch * 512, vf);
    #pragma unroll
    for (int q = 0; q < 8; ++q) acc = fmaf(wf[q], vf[q], acc);
  }
  acc = wred(acc);
  if (lane == 0) lin[j] = U[(size_t)j * TT + t] + acc;
}

template<typename WT>
__global__ void k_lstm_t(const WT* __restrict__ Wih_l, const WT* __restrict__ Whh_l,
                         const float* __restrict__ bih_l, const float* __restrict__ bhh_l,
                         const float* __restrict__ vin, const float* __restrict__ hprev,
                         float* __restrict__ c, float* __restrict__ hout)
{
  __shared__ float gsm[4];
  const int j    = blockIdx.x;
  const int g    = threadIdx.x >> 6;
  const int lane = threadIdx.x & 63;
  const WT* wi = Wih_l + (size_t)(g * NN + j) * NN + lane * 8;
  const WT* wh = Whh_l + (size_t)(g * NN + j) * NN + lane * 8;
  const float* vi = vin + lane * 8;
  const float* hp = hprev + lane * 8;
  float acc = 0.f;
  #pragma unroll
  for (int ch = 0; ch < 4; ++ch){
    float w1[8], w2[8], v1[8], v2[8];
    load8f(wi + ch * 512, w1); load8f(vi + ch * 512, v1);
    load8f(wh + ch * 512, w2); load8f(hp + ch * 512, v2);
    #pragma unroll
    for (int q = 0; q < 8; ++q) acc = fmaf(w1[q], v1[q], fmaf(w2[q], v2[q], acc));
  }
  acc = wred(acc);
  if (lane == 0) gsm[g] = acc + bih_l[g * NN + j] + bhh_l[g * NN + j];
  __syncthreads();
  if (threadIdx.x == 0){
    float gi = sigm(gsm[0]);
    float gf = sigm(gsm[1]);
    float gg = tanhf(gsm[2]);
    float go = sigm(gsm[3]);
    float cn = fmaf(gf, c[j], gi * gg);
    c[j] = cn;
    hout[j] = go * tanhf(cn);
  }
}

template<typename WT>
__global__ void k_xout_t(const WT* __restrict__ Wout, const float* __restrict__ bout,
                         const float* __restrict__ h1, float* __restrict__ xs,
                         float* __restrict__ out, int t)
{
  const int j    = blockIdx.x * 4 + (threadIdx.x >> 6);
  const int lane = threadIdx.x & 63;
  const WT* w = Wout + (size_t)j * NN + lane * 8;
  const float* hv = h1 + lane * 8;
  float acc = 0.f;
  #pragma unroll
  for (int ch = 0; ch < 4; ++ch){
    float wf[8], vf[8];
    load8f(w + ch * 512, wf);
    load8f(hv + ch * 512, vf);
    #pragma unroll
    for (int q = 0; q < 8; ++q) acc = fmaf(wf[q], vf[q], acc);
  }
  acc = wred(acc);
  if (lane == 0){
    float xn = xs[j] + tanhf(acc + bout[j]);
    xs[j] = xn;
    out[(size_t)j * (TT + 1) + t + 1] = xn;
  }
}

extern "C" void kernel_launch(void* const* d_in, const int* in_sizes, int n_in,
                              void* d_out, int out_size, void* d_ws, size_t ws_size,
                              hipStream_t stream)
{
  const float* x      = (const float*)d_in[0];
  const float* coords = (const float*)d_in[1];
  const float* env    = (const float*)d_in[2];
  const float* dusk   = (const float*)d_in[3];
  const float* dawn   = (const float*)d_in[4];
  const float* Win    = (const float*)d_in[5];
  const float* bin    = (const float*)d_in[6];
  const float* Wih    = (const float*)d_in[7];
  const float* Whh    = (const float*)d_in[8];
  const float* bih    = (const float*)d_in[9];
  const float* bhh    = (const float*)d_in[10];
  const float* Wout   = (const float*)d_in[11];
  const float* bout   = (const float*)d_in[12];
  float* out = (float*)d_out;

  // ---- f32 scratch layout
  float* ws  = (float*)d_ws;
  float* S   = ws;                          // 30720*64
  float* P   = S + (size_t)KSTAT * TT;      // 8*2048*64
  float* U   = P + (size_t)KPART * NN * TT; // 131072
  float* lin = U + (size_t)NN * TT;
  float* h0b = lin + NN;
  float* h1b = h0b + 2 * NN;
  float* c0  = h1b + 2 * NN;
  float* c1  = c0 + NN;
  float* xs  = c1 + NN;
  char*  f32_end = (char*)(xs + NN);
  const size_t f32_bytes = (size_t)(f32_end - (char*)d_ws);

  // ---- packed int10 weights + per-row scales
  const size_t rows_ihhh = (size_t)2 * 4 * NN;          // 16384 rows per matrix
  const size_t pw_ihhh   = rows_ihhh * RWORDS * 4;      // 41.9 MB each
  const size_t pw_small  = (size_t)NN * RWORDS * 4;     // 5.24 MB each

  uint32* PIH = (uint32*)((char*)d_ws + f32_bytes);
  uint32* PHH = (uint32*)((char*)PIH + pw_ihhh);
  uint32* PT  = (uint32*)((char*)PHH + pw_ihhh);
  uint32* PO  = (uint32*)((char*)PT + pw_small);
  float*  sc_ih = (float*)((char*)PO + pw_small);       // 16384
  float*  sc_hh = sc_ih + rows_ihhh;                    // 16384
  float*  sc_t  = sc_hh + rows_ihhh;                    // 2048
  float*  sc_o  = sc_t + NN;                            // 2048
  const size_t needed = f32_bytes + 2 * pw_ihhh + 2 * pw_small
                      + (2 * rows_ihhh + 2 * NN) * sizeof(float);
  const bool use_q = (ws_size >= needed);

  if (use_q){
    // 16384 + 16384 + 2048 + 2048 = 36864 rows, 4 rows/block
    k_pack_all<<<dim3(36864 / 4), dim3(256), 0, stream>>>(
        Wih, Whh, Win, Wout, PIH, PHH, PT, PO, sc_ih, sc_hh, sc_t, sc_o);
  }

  k_gather<<<dim3((KSTAT * TT) / 256), dim3(256), 0, stream>>>(coords, env, dusk, dawn, S);
  k_pre<<<dim3(128, KPART), dim3(256), 0, stream>>>(Win, S, P);
  k_reduce_init<<<dim3(NN * TT / 256), dim3(256), 0, stream>>>(P, bin, U, x, xs,
                                                               h0b, h1b, c0, c1, out);

  const size_t LROWS = (size_t)4 * NN;   // row offset for layer 1
  for (int t = 0; t < TT; ++t){
    const int p = t & 1;
    float* h0n = h0b + (1 - p) * NN;
    float* h0p = h0b + p * NN;
    float* h1n = h1b + (1 - p) * NN;
    float* h1p = h1b + p * NN;
    if (use_q){
      k_lin10<<<dim3(NN / 4), dim3(256), 0, stream>>>(PT, sc_t, U, xs, lin, t);
      k_lstm10<<<dim3(NN), dim3(256), 0, stream>>>(PIH, PHH, sc_ih, sc_hh,
                                                   bih, bhh, lin, h0p, c0, h0n);
      k_lstm10<<<dim3(NN), dim3(256), 0, stream>>>(PIH + LROWS * RWORDS, PHH + LROWS * RWORDS,
                                                   sc_ih + LROWS, sc_hh + LROWS,
                                                   bih + 4 * NN, bhh + 4 * NN,
                                                   h0n, h1p, c1, h1n);
      k_xout10<<<dim3(NN / 4), dim3(256), 0, stream>>>(PO, sc_o, bout, h1n, xs, out, t);
    } else {
      const size_t LOFF = (size_t)4 * NN * NN;
      k_lin_t<float><<<dim3(NN / 4), dim3(256), 0, stream>>>(Win + KSTAT, (size_t)KIN, U, xs, lin, t);
      k_lstm_t<float><<<dim3(NN), dim3(256), 0, stream>>>(Wih, Whh, bih, bhh,
                                                          lin, h0p, c0, h0n);
      k_lstm_t<float><<<dim3(NN), dim3(256), 0, stream>>>(Wih + LOFF, Whh + LOFF,
                                                          bih + 4 * NN, bhh + 4 * NN,
                                                          h0n, h1p, c1, h1n);
      k_xout_t<float><<<dim3(NN / 4), dim3(256), 0, stream>>>(Wout, bout, h1n, xs, out, t);
    }
  }
}

// Round 11
// 1852.907 us; speedup vs baseline: 1.1205x; 1.0312x over previous
//
#include <hip/hip_runtime.h>
#include <math.h>

#define NN    2048      // nodes == hidden
#define TT    64        // horizon
#define KIN   32768     // N_IN * N_NODES
#define KSTAT 30720     // static (non-recurrent) part of W_in columns
#define KPART 8         // K-split for k_pre
#define KC    (KSTAT / KPART)   // 3840
#define RW9   576       // dwords per packed int9 row (64 lanes * 9)

typedef unsigned int uint32;

__device__ __forceinline__ float wred(float v){
  #pragma unroll
  for (int m = 32; m > 0; m >>= 1) v += __shfl_xor(v, m, 64);
  return v;
}
__device__ __forceinline__ float wredmax(float v){
  #pragma unroll
  for (int m = 32; m > 0; m >>= 1) v = fmaxf(v, __shfl_xor(v, m, 64));
  return v;
}
__device__ __forceinline__ float sigm(float x){ return 1.0f / (1.0f + expf(-x)); }

__device__ __forceinline__ void load8f(const float* __restrict__ p, float* o){
  float4 a = *(const float4*)p, b = *(const float4*)(p + 4);
  o[0]=a.x; o[1]=a.y; o[2]=a.z; o[3]=a.w; o[4]=b.x; o[5]=b.y; o[6]=b.z; o[7]=b.w;
}

// ---------- single pack kernel for all 4 matrices (int9, per-row scale) ----------
// Lane owns weights {4*(lane+64c)+q : c=0..7,q=0..3}; field order k=4c+q.
// Row storage per lane: plane0 uint4 (u0..u3), plane1 uint4 (u4..u7), plane2 uint1 (u8).
__global__ void k_pack_all(const float* __restrict__ Wih, const float* __restrict__ Whh,
                           const float* __restrict__ Win, const float* __restrict__ Wout,
                           uint32* __restrict__ PIH, uint32* __restrict__ PHH,
                           uint32* __restrict__ PT,  uint32* __restrict__ PO,
                           float* __restrict__ sc_ih, float* __restrict__ sc_hh,
                           float* __restrict__ sc_t,  float* __restrict__ sc_o)
{
  const int gr   = blockIdx.x * 4 + (threadIdx.x >> 6);   // 0..36863
  const int lane = threadIdx.x & 63;
  const float* src; uint32* dst; float* sc;
  if (gr < 16384){        int r = gr;         src = Wih  + (size_t)r * NN;          dst = PIH + (size_t)r * RW9; sc = sc_ih + r; }
  else if (gr < 32768){   int r = gr - 16384; src = Whh  + (size_t)r * NN;          dst = PHH + (size_t)r * RW9; sc = sc_hh + r; }
  else if (gr < 34816){   int r = gr - 32768; src = Win  + (size_t)r * KIN + KSTAT; dst = PT  + (size_t)r * RW9; sc = sc_t  + r; }
  else {                  int r = gr - 34816; src = Wout + (size_t)r * NN;          dst = PO  + (size_t)r * RW9; sc = sc_o  + r; }

  float w[32];
  float m = 0.f;
  #pragma unroll
  for (int c = 0; c < 8; ++c){
    float4 v = *(const float4*)(src + 4 * (lane + (c << 6)));
    w[4*c+0] = v.x; w[4*c+1] = v.y; w[4*c+2] = v.z; w[4*c+3] = v.w;
    m = fmaxf(m, fmaxf(fmaxf(fabsf(v.x), fabsf(v.y)), fmaxf(fabsf(v.z), fabsf(v.w))));
  }
  m = wredmax(m);
  const float inv = (m > 0.f) ? 255.f / m : 0.f;
  if (lane == 0) *sc = (m > 0.f) ? m / 255.f : 0.f;

  uint32 u[9] = {0,0,0,0,0,0,0,0,0};
  #pragma unroll
  for (int k = 0; k < 32; ++k){
    int q = (int)rintf(w[k] * inv) + 256;
    q = (q < 0) ? 0 : ((q > 511) ? 511 : q);
    uint32 f = (uint32)q;
    int bp = 9 * k, wd = bp >> 5, off = bp & 31;
    u[wd] |= f << off;
    if (off > 23) u[wd + 1] |= f >> (32 - off);
  }
  *(uint4*)(dst + lane * 4)        = make_uint4(u[0], u[1], u[2], u[3]);
  *(uint4*)(dst + 256 + lane * 4)  = make_uint4(u[4], u[5], u[6], u[7]);
  dst[512 + lane] = u[8];
}

// ---------- packed int9 dot: one wave, one row of 2048; returns UNSCALED sum ----------
__device__ __forceinline__ float dot9(const uint32* __restrict__ base, int row,
                                      const float4* __restrict__ v4, int lane){
  const uint32* p = base + (size_t)row * RW9;
  uint4 A = *(const uint4*)(p + lane * 4);
  uint4 B = *(const uint4*)(p + 256 + lane * 4);
  uint32 Cw = p[512 + lane];
  uint32 u[9] = {A.x,A.y,A.z,A.w, B.x,B.y,B.z,B.w, Cw};
  float acc = 0.f;
  #pragma unroll
  for (int c = 0; c < 8; ++c){
    float4 v = v4[lane + (c << 6)];
    float vv[4] = {v.x, v.y, v.z, v.w};
    #pragma unroll
    for (int q = 0; q < 4; ++q){
      int k = 4 * c + q, bp = 9 * k, wd = bp >> 5, off = bp & 31;
      uint32 f = u[wd] >> off;
      if (off > 23) f |= u[wd + 1] << (32 - off);   // folds at compile time
      f &= 511u;
      acc = fmaf((float)((int)f - 256), vv[q], acc);
    }
  }
  return acc;
}

// ---------- gather static input matrix S[k][t] ----------
__global__ void k_gather(const float* __restrict__ coords, const float* __restrict__ env,
                         const float* __restrict__ dusk, const float* __restrict__ dawn,
                         float* __restrict__ S)
{
  int idx = blockIdx.x * 256 + threadIdx.x;
  int k = idx >> 6, t = idx & 63;
  float v;
  if (k < 4096)        v = coords[k];
  else if (k < 26624)  v = env[(size_t)(k - 4096) * 65 + t + 1];
  else if (k < 28672)  v = dusk[(size_t)(k - 26624) * 64 + t];
  else                 v = dawn[(size_t)(k - 28672) * 65 + t + 1];
  S[idx] = v;
}

// ---------- tiled GEMM: P[part][r][t] = sum_{k in part} W_in[r][k] * S[k][t] ----------
__global__ void k_pre(const float* __restrict__ Win, const float* __restrict__ S,
                      float* __restrict__ P)
{
  __shared__ float Wt[16 * 68];
  __shared__ float St[64 * 68];
  const int tid = threadIdx.x;
  const int rb  = blockIdx.x * 16;
  const int kp  = blockIdx.y;
  const int rc  = tid >> 4;
  const int t4  = (tid & 15) * 4;
  float4 acc = make_float4(0.f, 0.f, 0.f, 0.f);

  for (int kt = 0; kt < KC; kt += 64){
    const int kb = kp * KC + kt;
    __syncthreads();
    *(float4*)(Wt + rc * 68 + t4) =
        *(const float4*)(Win + (size_t)(rb + rc) * KIN + kb + t4);
    #pragma unroll
    for (int jj = 0; jj < 4; ++jj){
      int li = jj * 1024 + tid * 4;
      int kr = li >> 6, tc = li & 63;
      *(float4*)(St + kr * 68 + tc) =
          *(const float4*)(S + (size_t)(kb + kr) * 64 + tc);
    }
    __syncthreads();
    #pragma unroll
    for (int k = 0; k < 64; ++k){
      float w = Wt[rc * 68 + k];
      float4 s = *(const float4*)(St + k * 68 + t4);
      acc.x = fmaf(w, s.x, acc.x);
      acc.y = fmaf(w, s.y, acc.y);
      acc.z = fmaf(w, s.z, acc.z);
      acc.w = fmaf(w, s.w, acc.w);
    }
  }
  *(float4*)(P + ((size_t)kp * NN + rb + rc) * TT + t4) = acc;
}

// ---------- U reduce + state/output init (fused) ----------
__global__ void k_reduce_init(const float* __restrict__ P, const float* __restrict__ bin,
                              float* __restrict__ U, const float* __restrict__ x,
                              float* __restrict__ xs, float* __restrict__ h0b,
                              float* __restrict__ h1b, float* __restrict__ c0,
                              float* __restrict__ c1, float* __restrict__ out)
{
  int i = blockIdx.x * 256 + threadIdx.x;            // 131072 total
  float s = bin[i >> 6];
  #pragma unroll
  for (int p = 0; p < KPART; ++p) s += P[(size_t)p * NN * TT + i];
  U[i] = s;
  if (i < NN){
    float x0 = x[(size_t)i * (TT + 1)];
    xs[i] = x0;
    out[(size_t)i * (TT + 1)] = x0;
    h0b[i] = 0.f; h0b[NN + i] = 0.f;
    h1b[i] = 0.f; h1b[NN + i] = 0.f;
    c0[i] = 0.f;  c1[i] = 0.f;
  }
}

// ---------- stage A: lin[j] = U[j][t] + scale_t[j] * (PT[j,:] . xs) ----------
__global__ void k_lin9(const uint32* __restrict__ PT, const float* __restrict__ sc_t,
                       const float* __restrict__ U, const float* __restrict__ xs,
                       float* __restrict__ lin, int t)
{
  const int j    = blockIdx.x * 4 + (threadIdx.x >> 6);
  const int lane = threadIdx.x & 63;
  float acc = wred(dot9(PT, j, (const float4*)xs, lane));
  if (lane == 0) lin[j] = U[(size_t)j * TT + t] + sc_t[j] * acc;
}

// ---------- LSTM layer: block per unit j, wave g per gate (direct global reads) ----------
__global__ void k_lstm9(const uint32* __restrict__ Pih, const uint32* __restrict__ Phh,
                        const float* __restrict__ sc_ih, const float* __restrict__ sc_hh,
                        const float* __restrict__ bih_l, const float* __restrict__ bhh_l,
                        const float* __restrict__ vin, const float* __restrict__ hprev,
                        float* __restrict__ c, float* __restrict__ hout)
{
  __shared__ float gsm[4];
  const int j    = blockIdx.x;
  const int g    = threadIdx.x >> 6;
  const int lane = threadIdx.x & 63;
  const int row  = g * NN + j;
  float a1 = dot9(Pih, row, (const float4*)vin,   lane);
  float a2 = dot9(Phh, row, (const float4*)hprev, lane);
  float acc = wred(sc_ih[row] * a1 + sc_hh[row] * a2);
  if (lane == 0) gsm[g] = acc + bih_l[g * NN + j] + bhh_l[g * NN + j];
  __syncthreads();
  if (threadIdx.x == 0){
    float gi = sigm(gsm[0]);
    float gf = sigm(gsm[1]);
    float gg = tanhf(gsm[2]);
    float go = sigm(gsm[3]);
    float cn = fmaf(gf, c[j], gi * gg);
    c[j] = cn;
    hout[j] = go * tanhf(cn);
  }
}

// ---------- stage D: x += tanh(scale_o[j]*(PO[j,:] . h1) + b_out) ----------
__global__ void k_xout9(const uint32* __restrict__ PO, const float* __restrict__ sc_o,
                        const float* __restrict__ bout, const float* __restrict__ h1,
                        float* __restrict__ xs, float* __restrict__ out, int t)
{
  const int j    = blockIdx.x * 4 + (threadIdx.x >> 6);
  const int lane = threadIdx.x & 63;
  float acc = wred(dot9(PO, j, (const float4*)h1, lane));
  if (lane == 0){
    float xn = xs[j] + tanhf(sc_o[j] * acc + bout[j]);
    xs[j] = xn;
    out[(size_t)j * (TT + 1) + t + 1] = xn;
  }
}

// ---------- f32 fallback kernels (used only if ws too small) ----------
template<typename WT>
__global__ void k_lin_t(const WT* __restrict__ Wtail, size_t wstride,
                        const float* __restrict__ U, const float* __restrict__ xs,
                        float* __restrict__ lin, int t)
{
  const int j    = blockIdx.x * 4 + (threadIdx.x >> 6);
  const int lane = threadIdx.x & 63;
  const WT* w = Wtail + (size_t)j * wstride + lane * 8;
  const float* xv = xs + lane * 8;
  float acc = 0.f;
  #pragma unroll
  for (int ch = 0; ch < 4; ++ch){
    float wf[8], vf[8];
    load8f(w + ch * 512, wf);
    load8f(xv + ch * 512, vf);
    #pragma unroll
    for (int q = 0; q < 8; ++q) acc = fmaf(wf[q], vf[q], acc);
  }
  acc = wred(acc);
  if (lane == 0) lin[j] = U[(size_t)j * TT + t] + acc;
}

template<typename WT>
__global__ void k_lstm_t(const WT* __restrict__ Wih_l, const WT* __restrict__ Whh_l,
                         const float* __restrict__ bih_l, const float* __restrict__ bhh_l,
                         const float* __restrict__ vin, const float* __restrict__ hprev,
                         float* __restrict__ c, float* __restrict__ hout)
{
  __shared__ float gsm[4];
  const int j    = blockIdx.x;
  const int g    = threadIdx.x >> 6;
  const int lane = threadIdx.x & 63;
  const WT* wi = Wih_l + (size_t)(g * NN + j) * NN + lane * 8;
  const WT* wh = Whh_l + (size_t)(g * NN + j) * NN + lane * 8;
  const float* vi = vin + lane * 8;
  const float* hp = hprev + lane * 8;
  float acc = 0.f;
  #pragma unroll
  for (int ch = 0; ch < 4; ++ch){
    float w1[8], w2[8], v1[8], v2[8];
    load8f(wi + ch * 512, w1); load8f(vi + ch * 512, v1);
    load8f(wh + ch * 512, w2); load8f(hp + ch * 512, v2);
    #pragma unroll
    for (int q = 0; q < 8; ++q) acc = fmaf(w1[q], v1[q], fmaf(w2[q], v2[q], acc));
  }
  acc = wred(acc);
  if (lane == 0) gsm[g] = acc + bih_l[g * NN + j] + bhh_l[g * NN + j];
  __syncthreads();
  if (threadIdx.x == 0){
    float gi = sigm(gsm[0]);
    float gf = sigm(gsm[1]);
    float gg = tanhf(gsm[2]);
    float go = sigm(gsm[3]);
    float cn = fmaf(gf, c[j], gi * gg);
    c[j] = cn;
    hout[j] = go * tanhf(cn);
  }
}

template<typename WT>
__global__ void k_xout_t(const WT* __restrict__ Wout, const float* __restrict__ bout,
                         const float* __restrict__ h1, float* __restrict__ xs,
                         float* __restrict__ out, int t)
{
  const int j    = blockIdx.x * 4 + (threadIdx.x >> 6);
  const int lane = threadIdx.x & 63;
  const WT* w = Wout + (size_t)j * NN + lane * 8;
  const float* hv = h1 + lane * 8;
  float acc = 0.f;
  #pragma unroll
  for (int ch = 0; ch < 4; ++ch){
    float wf[8], vf[8];
    load8f(w + ch * 512, wf);
    load8f(hv + ch * 512, vf);
    #pragma unroll
    for (int q = 0; q < 8; ++q) acc = fmaf(wf[q], vf[q], acc);
  }
  acc = wred(acc);
  if (lane == 0){
    float xn = xs[j] + tanhf(acc + bout[j]);
    xs[j] = xn;
    out[(size_t)j * (TT + 1) + t + 1] = xn;
  }
}

extern "C" void kernel_launch(void* const* d_in, const int* in_sizes, int n_in,
                              void* d_out, int out_size, void* d_ws, size_t ws_size,
                              hipStream_t stream)
{
  const float* x      = (const float*)d_in[0];
  const float* coords = (const float*)d_in[1];
  const float* env    = (const float*)d_in[2];
  const float* dusk   = (const float*)d_in[3];
  const float* dawn   = (const float*)d_in[4];
  const float* Win    = (const float*)d_in[5];
  const float* bin    = (const float*)d_in[6];
  const float* Wih    = (const float*)d_in[7];
  const float* Whh    = (const float*)d_in[8];
  const float* bih    = (const float*)d_in[9];
  const float* bhh    = (const float*)d_in[10];
  const float* Wout   = (const float*)d_in[11];
  const float* bout   = (const float*)d_in[12];
  float* out = (float*)d_out;

  // ---- f32 scratch layout
  float* ws  = (float*)d_ws;
  float* S   = ws;                          // 30720*64
  float* P   = S + (size_t)KSTAT * TT;      // 8*2048*64
  float* U   = P + (size_t)KPART * NN * TT; // 131072
  float* lin = U + (size_t)NN * TT;
  float* h0b = lin + NN;
  float* h1b = h0b + 2 * NN;
  float* c0  = h1b + 2 * NN;
  float* c1  = c0 + NN;
  float* xs  = c1 + NN;
  char*  f32_end = (char*)(xs + NN);
  const size_t f32_bytes = (size_t)(f32_end - (char*)d_ws);

  // ---- packed int9 weights + per-row scales
  const size_t rows_ihhh = (size_t)2 * 4 * NN;          // 16384 rows per matrix
  const size_t pw_ihhh   = rows_ihhh * RW9 * 4;         // 37.7 MB each
  const size_t pw_small  = (size_t)NN * RW9 * 4;        // 4.7 MB each

  uint32* PIH = (uint32*)((char*)d_ws + f32_bytes);
  uint32* PHH = (uint32*)((char*)PIH + pw_ihhh);
  uint32* PT  = (uint32*)((char*)PHH + pw_ihhh);
  uint32* PO  = (uint32*)((char*)PT + pw_small);
  float*  sc_ih = (float*)((char*)PO + pw_small);       // 16384
  float*  sc_hh = sc_ih + rows_ihhh;                    // 16384
  float*  sc_t  = sc_hh + rows_ihhh;                    // 2048
  float*  sc_o  = sc_t + NN;                            // 2048
  const size_t needed = f32_bytes + 2 * pw_ihhh + 2 * pw_small
                      + (2 * rows_ihhh + 2 * NN) * sizeof(float);
  const bool use_q = (ws_size >= needed);

  if (use_q){
    // 16384 + 16384 + 2048 + 2048 = 36864 rows, 4 rows/block
    k_pack_all<<<dim3(36864 / 4), dim3(256), 0, stream>>>(
        Wih, Whh, Win, Wout, PIH, PHH, PT, PO, sc_ih, sc_hh, sc_t, sc_o);
  }

  k_gather<<<dim3((KSTAT * TT) / 256), dim3(256), 0, stream>>>(coords, env, dusk, dawn, S);
  k_pre<<<dim3(128, KPART), dim3(256), 0, stream>>>(Win, S, P);
  k_reduce_init<<<dim3(NN * TT / 256), dim3(256), 0, stream>>>(P, bin, U, x, xs,
                                                               h0b, h1b, c0, c1, out);

  const size_t LROWS = (size_t)4 * NN;   // row offset for layer 1
  for (int t = 0; t < TT; ++t){
    const int p = t & 1;
    float* h0n = h0b + (1 - p) * NN;
    float* h0p = h0b + p * NN;
    float* h1n = h1b + (1 - p) * NN;
    float* h1p = h1b + p * NN;
    if (use_q){
      k_lin9<<<dim3(NN / 4), dim3(256), 0, stream>>>(PT, sc_t, U, xs, lin, t);
      k_lstm9<<<dim3(NN), dim3(256), 0, stream>>>(PIH, PHH, sc_ih, sc_hh,
                                                  bih, bhh, lin, h0p, c0, h0n);
      k_lstm9<<<dim3(NN), dim3(256), 0, stream>>>(PIH + LROWS * RW9, PHH + LROWS * RW9,
                                                  sc_ih + LROWS, sc_hh + LROWS,
                                                  bih + 4 * NN, bhh + 4 * NN,
                                                  h0n, h1p, c1, h1n);
      k_xout9<<<dim3(NN / 4), dim3(256), 0, stream>>>(PO, sc_o, bout, h1n, xs, out, t);
    } else {
      const size_t LOFF = (size_t)4 * NN * NN;
      k_lin_t<float><<<dim3(NN / 4), dim3(256), 0, stream>>>(Win + KSTAT, (size_t)KIN, U, xs, lin, t);
      k_lstm_t<float><<<dim3(NN), dim3(256), 0, stream>>>(Wih, Whh, bih, bhh,
                                                          lin, h0p, c0, h0n);
      k_lstm_t<float><<<dim3(NN), dim3(256), 0, stream>>>(Wih + LOFF, Whh + LOFF,
                                                          bih + 4 * NN, bhh + 4 * NN,
                                                          h0n, h1p, c1, h1n);
      k_xout_t<float><<<dim3(NN / 4), dim3(256), 0, stream>>>(Wout, bout, h1n, xs, out, t);
    }
  }
}